// Round 4
// baseline (685.289 us; speedup 1.0000x reference)
//
#include <hip/hip_runtime.h>
#include <cstdint>
#include <cstddef>

typedef short bf16x8 __attribute__((ext_vector_type(8)));
typedef float f32x4 __attribute__((ext_vector_type(4)));

#define B_ 2
#define T_ 2048
#define DIN 2048
#define H_ 32
#define HD_ 64
#define KV_ 8

__device__ __forceinline__ unsigned short f2b(float f) {
  unsigned int u = __float_as_uint(f);
  u += 0x7fffu + ((u >> 16) & 1u);
  return (unsigned short)(u >> 16);
}

__device__ __forceinline__ float b2f(unsigned short b) {
  return __uint_as_float(((unsigned int)b) << 16);
}

__device__ __forceinline__ void gload_lds16(const void* g, void* l) {
  __builtin_amdgcn_global_load_lds(
      (const unsigned int __attribute__((address_space(1)))*)g,
      (unsigned int __attribute__((address_space(3)))*)l, 16, 0, 0);
}

__global__ __launch_bounds__(256) void cvt_bf16(const float* __restrict__ in,
                                                unsigned short* __restrict__ out,
                                                int n4) {
  int i = blockIdx.x * 256 + threadIdx.x;
  if (i >= n4) return;
  float4 v = ((const float4*)in)[i];
  uint2 o;
  o.x = (unsigned)f2b(v.x) | ((unsigned)f2b(v.y) << 16);
  o.y = (unsigned)f2b(v.z) | ((unsigned)f2b(v.w) << 16);
  ((uint2*)out)[i] = o;
}

// C[M][N] = A[M][K] * Bw[N][K]^T (+bias). bf16 inputs; f32 or bf16 out.
__global__ __launch_bounds__(256) void gemm_bt(const unsigned short* __restrict__ A,
                                               const unsigned short* __restrict__ Bw,
                                               const float* __restrict__ bias,
                                               void* __restrict__ Cout,
                                               int M, int N, int K, int out_bf16) {
  __shared__ short As[128 * 64];
  __shared__ short Bs[128 * 64];
  const int tid = threadIdx.x;
  const int lane = tid & 63;
  const int wid = tid >> 6;
  const int wr = (wid >> 1) * 64;
  const int wc = (wid & 1) * 64;
  const int bm = blockIdx.y * 128;
  const int bn = blockIdx.x * 128;
  const int lr = lane & 15;
  const int lk = (lane >> 4) * 8;
  f32x4 acc[4][4] = {};

  for (int kt = 0; kt < K; kt += 64) {
    __syncthreads();
#pragma unroll
    for (int it = 0; it < 4; ++it) {
      int c = it * 256 + tid;
      int r = c >> 3;
      int c8 = (c & 7) * 8;
      gload_lds16(A + (size_t)(bm + r) * K + kt + c8, &As[c * 8]);
      gload_lds16(Bw + (size_t)(bn + r) * K + kt + c8, &Bs[c * 8]);
    }
    __syncthreads();
#pragma unroll
    for (int kk = 0; kk < 2; ++kk) {
      bf16x8 af[4], bfr[4];
#pragma unroll
      for (int m = 0; m < 4; ++m)
        af[m] = *(const bf16x8*)&As[(wr + m * 16 + lr) * 64 + kk * 32 + lk];
#pragma unroll
      for (int n = 0; n < 4; ++n)
        bfr[n] = *(const bf16x8*)&Bs[(wc + n * 16 + lr) * 64 + kk * 32 + lk];
#pragma unroll
      for (int m = 0; m < 4; ++m)
#pragma unroll
        for (int n = 0; n < 4; ++n)
          acc[m][n] = __builtin_amdgcn_mfma_f32_16x16x32_bf16(af[m], bfr[n], acc[m][n], 0, 0, 0);
    }
  }
  const int r0 = bm + wr + (lane >> 4) * 4;
  const int c0 = bn + wc + lr;
#pragma unroll
  for (int m = 0; m < 4; ++m)
#pragma unroll
    for (int n = 0; n < 4; ++n) {
      int col = c0 + n * 16;
      float bb = bias ? bias[col] : 0.0f;
#pragma unroll
      for (int r = 0; r < 4; ++r) {
        float val = acc[m][n][r] + bb;
        size_t idx = (size_t)(r0 + m * 16 + r) * N + col;
        if (out_bf16)
          ((unsigned short*)Cout)[idx] = f2b(val);
        else
          ((float*)Cout)[idx] = val;
      }
    }
}

// bias + RoPE + scatter into attention layouts; K/V also to f32 outputs.
// cqkv is bf16 here.
__global__ __launch_bounds__(256) void rope_scatter(
    const unsigned short* __restrict__ cqkv, const float* __restrict__ bq,
    const float* __restrict__ bk, const float* __restrict__ bv,
    const float* __restrict__ cosp, const float* __restrict__ sinp,
    unsigned short* __restrict__ qbuf, unsigned short* __restrict__ kbuf,
    unsigned short* __restrict__ vbuf, float* __restrict__ kout,
    float* __restrict__ vout) {
  const int bt = blockIdx.x;
  const int b = bt >> 11;
  const int t = bt & 2047;
  const int tid = threadIdx.x;
  const unsigned short* row = cqkv + (size_t)bt * 3072;

  // Q: 1024 rope pairs, scaled by 1/8 (exact in bf16)
  for (int p = tid; p < 1024; p += 256) {
    int h = p >> 5, i = p & 31;
    float c = cosp[t * 32 + i], s = sinp[t * 32 + i];
    float q0 = b2f(row[2 * p]) + bq[2 * p];
    float q1 = b2f(row[2 * p + 1]) + bq[2 * p + 1];
    float qe = (q0 * c - q1 * s) * 0.125f;
    float qo = (q0 * s + q1 * c) * 0.125f;
    size_t base = ((size_t)(b * H_ + h) * T_ + t) * HD_ + 2 * i;
    qbuf[base] = f2b(qe);
    qbuf[base + 1] = f2b(qo);
  }
  // K: 256 rope pairs
  {
    int p = tid;
    if (p < 256) {
      int kvh = p >> 5, i = p & 31;
      float c = cosp[t * 32 + i], s = sinp[t * 32 + i];
      float k0 = b2f(row[2048 + 2 * p]) + bk[2 * p];
      float k1 = b2f(row[2048 + 2 * p + 1]) + bk[2 * p + 1];
      float ke = k0 * c - k1 * s;
      float ko = k0 * s + k1 * c;
      size_t base = ((size_t)(b * KV_ + kvh) * T_ + t) * HD_ + 2 * i;
      kout[base] = ke;
      kout[base + 1] = ko;
      kbuf[base] = f2b(ke);
      kbuf[base + 1] = f2b(ko);
    }
  }
  // V: 512 elems
  for (int j = tid; j < 512; j += 256) {
    int kvh = j >> 6, d = j & 63;
    float v = b2f(row[2560 + j]) + bv[j];
    size_t base = ((size_t)(b * KV_ + kvh) * T_ + t) * HD_ + d;
    vout[base] = v;
    vbuf[base] = f2b(v);
  }
}

// Causal GQA flash attention. grid(qtile=T/64, H, B), 256 thr = 4 waves x 16 q-rows.
__global__ __launch_bounds__(256) void attn(const unsigned short* __restrict__ Q,
                                            const unsigned short* __restrict__ Kb,
                                            const unsigned short* __restrict__ Vb,
                                            unsigned short* __restrict__ ctx) {
  __shared__ short Vt[64 * 64];      // V^T tile: [hd][kv]
  __shared__ short Pw[4][16 * 64];   // per-wave P tile: [qrow][kv]
  const int qtile = blockIdx.x, h = blockIdx.y, bz = blockIdx.z;
  const int kvh = h >> 2;
  const int tid = threadIdx.x, lane = tid & 63, w = tid >> 6;
  const int lr = lane & 15;
  const int lk = (lane >> 4) * 8;
  const float NEGINF = -__builtin_inff();

  const unsigned short* qbase =
      Q + ((size_t)(bz * H_ + h) * T_ + qtile * 64 + w * 16) * HD_;
  bf16x8 qf[2];
  qf[0] = *(const bf16x8*)(qbase + (size_t)lr * HD_ + lk);
  qf[1] = *(const bf16x8*)(qbase + (size_t)lr * HD_ + 32 + lk);

  float mrun[4] = {NEGINF, NEGINF, NEGINF, NEGINF};
  float lrun[4] = {0.f, 0.f, 0.f, 0.f};
  f32x4 acc[4] = {};

  const unsigned short* kb = Kb + (size_t)(bz * KV_ + kvh) * T_ * HD_;
  const unsigned short* vb = Vb + (size_t)(bz * KV_ + kvh) * T_ * HD_;

  for (int kt = 0; kt <= qtile; ++kt) {
    __syncthreads();
    // stage V^T into LDS
#pragma unroll
    for (int it = 0; it < 2; ++it) {
      int c = it * 256 + tid;
      int vr = c >> 3;
      int c8 = (c & 7) * 8;
      bf16x8 v = *(const bf16x8*)(vb + (size_t)(kt * 64 + vr) * HD_ + c8);
#pragma unroll
      for (int j = 0; j < 8; ++j) Vt[(c8 + j) * 64 + vr] = v[j];
    }
    __syncthreads();

    // scores: S[16 q][64 kv] per wave
    f32x4 s[4];
#pragma unroll
    for (int cb = 0; cb < 4; ++cb) {
      s[cb] = (f32x4){0.f, 0.f, 0.f, 0.f};
#pragma unroll
      for (int kk = 0; kk < 2; ++kk) {
        bf16x8 kf = *(const bf16x8*)(kb + (size_t)(kt * 64 + cb * 16 + lr) * HD_ +
                                     kk * 32 + lk);
        s[cb] = __builtin_amdgcn_mfma_f32_16x16x32_bf16(qf[kk], kf, s[cb], 0, 0, 0);
      }
    }
    if (kt == qtile) {  // causal mask on diagonal tile
#pragma unroll
      for (int cb = 0; cb < 4; ++cb) {
        int col = kt * 64 + cb * 16 + lr;
#pragma unroll
        for (int r = 0; r < 4; ++r) {
          int rowq = qtile * 64 + w * 16 + (lane >> 4) * 4 + r;
          if (col > rowq) s[cb][r] = NEGINF;
        }
      }
    }
    // online softmax (rows live in 16-lane groups)
#pragma unroll
    for (int r = 0; r < 4; ++r) {
      float v = fmaxf(fmaxf(s[0][r], s[1][r]), fmaxf(s[2][r], s[3][r]));
      v = fmaxf(v, __shfl_xor(v, 1));
      v = fmaxf(v, __shfl_xor(v, 2));
      v = fmaxf(v, __shfl_xor(v, 4));
      v = fmaxf(v, __shfl_xor(v, 8));
      float mnew = fmaxf(mrun[r], v);
      float sc = __expf(mrun[r] - mnew);
      mrun[r] = mnew;
      float ps = 0.f;
#pragma unroll
      for (int cb = 0; cb < 4; ++cb) {
        float p = __expf(s[cb][r] - mnew);
        s[cb][r] = p;
        ps += p;
      }
      ps += __shfl_xor(ps, 1);
      ps += __shfl_xor(ps, 2);
      ps += __shfl_xor(ps, 4);
      ps += __shfl_xor(ps, 8);
      lrun[r] = lrun[r] * sc + ps;
#pragma unroll
      for (int cb = 0; cb < 4; ++cb) {
        acc[cb][r] *= sc;
        Pw[w][((lane >> 4) * 4 + r) * 64 + cb * 16 + lr] = (short)f2b(s[cb][r]);
      }
    }
    // PV: ctx[16 q][64 hd] += P[16][64] @ V[64][64]
    bf16x8 pa[2];
    pa[0] = *(const bf16x8*)&Pw[w][lr * 64 + lk];
    pa[1] = *(const bf16x8*)&Pw[w][lr * 64 + 32 + lk];
#pragma unroll
    for (int cb = 0; cb < 4; ++cb) {
      bf16x8 vf0 = *(const bf16x8*)&Vt[(cb * 16 + lr) * 64 + lk];
      bf16x8 vf1 = *(const bf16x8*)&Vt[(cb * 16 + lr) * 64 + 32 + lk];
      acc[cb] = __builtin_amdgcn_mfma_f32_16x16x32_bf16(pa[0], vf0, acc[cb], 0, 0, 0);
      acc[cb] = __builtin_amdgcn_mfma_f32_16x16x32_bf16(pa[1], vf1, acc[cb], 0, 0, 0);
    }
  }
  // epilogue: ctx[b][t][h*64+d] bf16
#pragma unroll
  for (int cb = 0; cb < 4; ++cb)
#pragma unroll
    for (int r = 0; r < 4; ++r) {
      int rowq = qtile * 64 + w * 16 + (lane >> 4) * 4 + r;
      ctx[((size_t)bz * T_ + rowq) * DIN + h * HD_ + cb * 16 + lr] =
          f2b(acc[cb][r] / lrun[r]);
    }
}

extern "C" void kernel_launch(void* const* d_in, const int* in_sizes, int n_in,
                              void* d_out, int out_size, void* d_ws, size_t ws_size,
                              hipStream_t stream) {
  const float* x = (const float*)d_in[0];
  const float* cosp = (const float*)d_in[1];
  const float* sinp = (const float*)d_in[2];
  const float* wq = (const float*)d_in[3];
  const float* bq = (const float*)d_in[4];
  const float* wk = (const float*)d_in[5];
  const float* bk = (const float*)d_in[6];
  const float* wv = (const float*)d_in[7];
  const float* bv = (const float*)d_in[8];
  const float* wo = (const float*)d_in[9];
  const float* bo = (const float*)d_in[10];

  float* out = (float*)d_out;
  float* kout = out + (size_t)B_ * T_ * DIN;
  float* vout = kout + (size_t)B_ * KV_ * T_ * HD_;

  // Workspace layout with reuse (peak 60 MB):
  //   region A @ 0MB  (16MB): xb      -> qbuf  (xb dead after gemm1)
  //   region B @ 16MB (12MB): wqkv    -> kbuf+vbuf (wqkv dead after gemm1)
  //   region C @ 28MB ( 8MB): wob     (static)
  //   region D @ 36MB (24MB): cqkv bf16 -> ctxb (cqkv dead after rope)
  char* ws = (char*)d_ws;
  unsigned short* xb   = (unsigned short*)(ws + 0);
  unsigned short* wqkv = (unsigned short*)(ws + (size_t)16 * 1024 * 1024);
  unsigned short* wob  = (unsigned short*)(ws + (size_t)28 * 1024 * 1024);
  unsigned short* cqkv = (unsigned short*)(ws + (size_t)36 * 1024 * 1024);

  unsigned short* qbuf = xb;                           // 8,388,608 elems (16MB)
  unsigned short* kbuf = wqkv;                         // 2,097,152 elems (4MB)
  unsigned short* vbuf = wqkv + (size_t)2097152;       // 2,097,152 elems (4MB)
  unsigned short* ctxb = cqkv;                         // 8,388,608 elems (16MB)

  // f32 -> bf16 conversions
  cvt_bf16<<<8192, 256, 0, stream>>>(x, xb, 2097152);
  cvt_bf16<<<4096, 256, 0, stream>>>(wq, wqkv, 1048576);
  // wk/wv: 512*2048 = 1,048,576 elems = 262,144 float4s each (round-3 bug: was half)
  cvt_bf16<<<1024, 256, 0, stream>>>(wk, wqkv + (size_t)2048 * 2048, 262144);
  cvt_bf16<<<1024, 256, 0, stream>>>(wv, wqkv + (size_t)2048 * 2048 + (size_t)512 * 2048, 262144);
  cvt_bf16<<<4096, 256, 0, stream>>>(wo, wob, 1048576);

  // QKV projection: (4096 x 2048) @ (3072 x 2048)^T -> bf16 cqkv
  gemm_bt<<<dim3(24, 32), 256, 0, stream>>>(xb, wqkv, nullptr, cqkv, 4096, 3072, 2048, 1);

  // bias + RoPE + scatter (reads cqkv, overwrites xb/wqkv regions; also f32 k/v out)
  rope_scatter<<<4096, 256, 0, stream>>>(cqkv, bq, bk, bv, cosp, sinp, qbuf, kbuf,
                                         vbuf, kout, vout);

  // causal GQA flash attention (writes ctxb over dead cqkv)
  attn<<<dim3(T_ / 64, H_, B_), 256, 0, stream>>>(qbuf, kbuf, vbuf, ctxb);

  // output projection: (4096 x 2048) @ (2048 x 2048)^T + bo -> f32 out
  gemm_bt<<<dim3(16, 32), 256, 0, stream>>>(ctxb, wob, bo, out, 4096, 2048, 2048, 0);
}